// Round 8
// baseline (176.537 us; speedup 1.0000x reference)
//
#include <hip/hip_runtime.h>
#include <hip/hip_bf16.h>
#include <hip/hip_fp16.h>
#include <hip/hip_cooperative_groups.h>

namespace cg = cooperative_groups;

#define N_NODES 10000
#define N_EDGES 160000
#define FDIM    512
#define MPAD    10112   // 158 * 64
#define NGRAPH  64
#define OUTF    128
#define PCHUNK  32      // pooling chunks per graph
#define PBLK    64      // preprocessing coop blocks

typedef __attribute__((ext_vector_type(8))) _Float16 f16x8;
typedef __attribute__((ext_vector_type(4))) float    f32x4;

__device__ __forceinline__ void gload_lds16(const void* g, void* l) {
    __builtin_amdgcn_global_load_lds(
        (const __attribute__((address_space(1))) void*)g,
        (__attribute__((address_space(3))) void*)l, 16, 0, 0);
}

// ---- cooperative preprocessing: histogram -> scan -> CSR scatter ------------
// P1 zero+detect+goff | P2 histogram | P3 block scan | P4 prefix+write | P5 scatter
__global__ __launch_bounds__(256) void prep_coop(
    const unsigned* __restrict__ eraw, const unsigned* __restrict__ braw,
    int* __restrict__ deg_cnt, int* __restrict__ goff, float* __restrict__ dinv,
    int* __restrict__ rowptr, int* __restrict__ fillcnt, int* __restrict__ col,
    int* __restrict__ blocksum) {
    cg::grid_group grid = cg::this_grid();
    __shared__ int s_is64;
    __shared__ int sums[256];
    __shared__ int s_pre;
    int t = threadIdx.x, blk = blockIdx.x;
    int tid = blk * 256 + t;                       // 0 .. 16383

    // P1: per-block dtype detect (no cross-block comm needed); zero; goff.
    if (t < 64) {
        // edge_index values are random in [0,10000): if int64, every high
        // word is zero; if int32, odd words are real data (~0 prob all-zero).
        unsigned v = eraw[2 * t + 1];
        unsigned long long b = __ballot(v != 0u);
        if (t == 0) s_is64 = (b == 0ull) ? 1 : 0;
    }
    __syncthreads();
    int is64 = s_is64;
    if (tid < N_NODES) deg_cnt[tid] = 0;
    if (tid >= N_NODES && tid < MPAD) dinv[tid] = 0.0f;   // pad rows scale to 0
    if (blk == 0 && t <= NGRAPH) {                 // batch sorted: binary search
        int lo = 0, hi = N_NODES;
        while (lo < hi) {
            int mid = (lo + hi) >> 1;
            int b = (int)(is64 ? braw[2 * mid] : braw[mid]);
            if (b < t) lo = mid + 1; else hi = mid;
        }
        goff[t] = lo;
    }
    grid.sync();

    // P2: degree histogram (grid-stride)
    for (int e = tid; e < N_EDGES; e += PBLK * 256) {
        unsigned d = is64 ? eraw[2 * (N_EDGES + e)] : eraw[N_EDGES + e];
        atomicAdd(&deg_cnt[d], 1);
    }
    grid.sync();

    // P3: one node per thread; intra-block inclusive scan (Hillis-Steele)
    int myv = (tid < N_NODES) ? deg_cnt[tid] : 0;
    sums[t] = myv;
    __syncthreads();
    for (int off = 1; off < 256; off <<= 1) {
        int v = (t >= off) ? sums[t - off] : 0;
        __syncthreads();
        sums[t] += v;
        __syncthreads();
    }
    int inc = sums[t];
    if (t == 255) blocksum[blk] = inc;
    grid.sync();

    // P4: wave-parallel block prefix; write rowptr/fillcnt/dinv
    if (t < 64) {
        int bs = blocksum[t];                      // PBLK == 64 lanes
        int v  = (t < blk) ? bs : 0;
        int vf = bs;
        #pragma unroll
        for (int off = 1; off < 64; off <<= 1) {
            v  += __shfl_xor(v,  off);
            vf += __shfl_xor(vf, off);
        }
        if (t == 0) s_pre = v;
        if (tid == 0) rowptr[N_NODES] = vf;
    }
    __syncthreads();
    int pre0 = s_pre;
    if (tid < N_NODES) {
        int pre = pre0 + inc - myv;                // exclusive prefix
        rowptr[tid] = pre; fillcnt[tid] = pre;
        dinv[tid] = rsqrtf((float)(myv + 1));      // +1 self-loop
    }
    grid.sync();

    // P5: CSR scatter
    for (int e = tid; e < N_EDGES; e += PBLK * 256) {
        unsigned s, d;
        if (is64) { s = eraw[2 * e]; d = eraw[2 * (N_EDGES + e)]; }
        else      { s = eraw[e];     d = eraw[N_EDGES + e]; }
        int idx = atomicAdd(&fillcnt[d], 1);
        col[idx] = (int)s;
    }
}

// W[k][n] (512x512 row-major) -> WT[n][k] as f16, LDS tile transpose
__global__ __launch_bounds__(256) void prep_w(
    const float* __restrict__ W1, const float* __restrict__ W2,
    _Float16* __restrict__ W1T, _Float16* __restrict__ W2T) {
    __shared__ float tile[64][65];
    const float* W = blockIdx.z ? W2 : W1;
    _Float16*   T  = blockIdx.z ? W2T : W1T;
    int r0 = blockIdx.y * 64, c0 = blockIdx.x * 64;
    int t = threadIdx.x;
    int col = t & 63, rr = t >> 6;
    #pragma unroll
    for (int i = 0; i < 16; ++i) {
        int row = i * 4 + rr;
        tile[row][col] = W[(size_t)(r0 + row) * 512 + c0 + col];   // coalesced read
    }
    __syncthreads();
    #pragma unroll
    for (int i = 0; i < 16; ++i) {
        int orow = i * 4 + rr;                                     // output row = orig col
        T[(size_t)(c0 + orow) * 512 + r0 + col] = (_Float16)tile[col][orow]; // coalesced write
    }
}

// -------- GEMM: C[r][c] = dinv[r] * (A[Mpad,512] @ B)[r][c]   (B as Bt[n][k])
// 64x128 tile, 632 blocks (2.47/CU). 4 waves: each owns 64 rows x 32 cols.
// AF32=1: A is f32 [N_NODES,512], converted to f16 during reg-staging.
#define BM 64
#define BN 128
#define BK 64

template<int AF32>
__global__ __launch_bounds__(256) void gemm_k(
    const void* __restrict__ Av, const _Float16* __restrict__ Bt,
    const float* __restrict__ dinv, _Float16* __restrict__ C) {
    __shared__ __align__(16) _Float16 Asm[BM * BK];
    __shared__ __align__(16) _Float16 Bsm[BN * BK];
    char* As = (char*)Asm;
    char* Bs = (char*)Bsm;
    const char* Ab = (const char*)Av;
    const char* Bb = (const char*)Bt;

    int tid  = threadIdx.x;
    int lane = tid & 63;
    int wave = tid >> 6;                    // 4 waves; wave w owns cols w*32..w*32+31

    // bijective XCD swizzle: NT=632, q=79, r=0 -> tile = xcd*79 + sub.
    const int NT = (MPAD / BM) * (FDIM / BN);          // 632
    int bid = blockIdx.x;
    int xcd = bid & 7, sub = bid >> 3;
    int q = NT >> 3, r = NT & 7;                       // 79, 0
    int base = (xcd < r) ? xcd * (q + 1) : r * (q + 1) + (xcd - r) * q;
    int tile = base + sub;
    int m0 = (tile >> 2) * BM;
    int n0 = (tile & 3) * BN;

    f32x4 acc[4][2] = {};

    for (int kt = 0; kt < FDIM; kt += BK) {
        if (AF32) {
            // reg-stage A: f32 global (linear) -> cvt f16 -> swizzled ds_write
            #pragma unroll
            for (int c = 0; c < 2; ++c) {
                int o   = (tid + c * 256) * 16;        // linear f16-tile byte offset
                int row = o >> 7;
                int cb  = o & 127;
                int gr  = m0 + row;
                f16x8 hv = (f16x8)0;
                if (gr < N_NODES) {
                    const float* sp = (const float*)(Ab + (size_t)gr * 2048 +
                                                     (size_t)kt * 4 + cb * 2);
                    float4 v0 = *(const float4*)sp;
                    float4 v1 = *(const float4*)(sp + 4);
                    hv[0] = (_Float16)v0.x; hv[1] = (_Float16)v0.y;
                    hv[2] = (_Float16)v0.z; hv[3] = (_Float16)v0.w;
                    hv[4] = (_Float16)v1.x; hv[5] = (_Float16)v1.y;
                    hv[6] = (_Float16)v1.z; hv[7] = (_Float16)v1.w;
                }
                *(f16x8*)(As + row * 128 + (cb ^ ((row & 7) << 4))) = hv;
            }
            #pragma unroll
            for (int i = 0; i < 4; ++i) {
                int o   = i * 4096 + wave * 1024 + lane * 16;
                int row = o >> 7;
                int cb  = o & 127;
                int scb = cb ^ ((row & 7) << 4);
                gload_lds16(Bb + (size_t)(n0 + row) * 1024 + kt * 2 + scb,
                            Bs + i * 4096 + wave * 1024);
            }
        } else {
            #pragma unroll
            for (int c = 0; c < 2; ++c) {          // A-tile: 8KB = 2 rounds
                int o   = c * 4096 + wave * 1024 + lane * 16;
                int row = o >> 7;
                int cb  = o & 127;
                int scb = cb ^ ((row & 7) << 4);
                gload_lds16(Ab + (size_t)(m0 + row) * 1024 + kt * 2 + scb,
                            As + c * 4096 + wave * 1024);
            }
            #pragma unroll
            for (int i = 0; i < 4; ++i) {          // B-tile: 16KB = 4 rounds
                int o   = i * 4096 + wave * 1024 + lane * 16;
                int row = o >> 7;
                int cb  = o & 127;
                int scb = cb ^ ((row & 7) << 4);
                gload_lds16(Bb + (size_t)(n0 + row) * 1024 + kt * 2 + scb,
                            Bs + i * 4096 + wave * 1024);
            }
        }
        __syncthreads();   // drains vmcnt + lgkmcnt before LDS reads

        #pragma unroll
        for (int kk = 0; kk < 2; ++kk) {
            f16x8 af[4], bf[2];
            int kb = kk * 64 + ((lane >> 4) << 4);        // byte offset in row
            #pragma unroll
            for (int fm = 0; fm < 4; ++fm) {              // rows 0..63 (broadcast across waves)
                int rr = fm * 16 + (lane & 15);
                af[fm] = *(const f16x8*)(As + rr * 128 + (kb ^ ((rr & 7) << 4)));
            }
            #pragma unroll
            for (int fn = 0; fn < 2; ++fn) {              // cols wave*32 + fn*16
                int rr = wave * 32 + fn * 16 + (lane & 15);
                bf[fn] = *(const f16x8*)(Bs + rr * 128 + (kb ^ ((rr & 7) << 4)));
            }
            #pragma unroll
            for (int fm = 0; fm < 4; ++fm)
                #pragma unroll
                for (int fn = 0; fn < 2; ++fn)
                    acc[fm][fn] = __builtin_amdgcn_mfma_f32_16x16x32_f16(
                        af[fm], bf[fn], acc[fm][fn], 0, 0, 0);
        }
        __syncthreads();
    }

    #pragma unroll
    for (int fm = 0; fm < 4; ++fm) {
        #pragma unroll
        for (int r4 = 0; r4 < 4; ++r4) {
            int row = m0 + fm * 16 + ((lane >> 4) << 2) + r4;
            float dr = dinv[row];
            #pragma unroll
            for (int fn = 0; fn < 2; ++fn) {
                int cn = n0 + wave * 32 + fn * 16 + (lane & 15);
                C[(size_t)row * FDIM + cn] = (_Float16)(acc[fm][fn][r4] * dr);
            }
        }
    }
}

// ---- propagation: z[d] = relu( dinv[d] * (sum_{s in N(d)} hs[s] + hs[d]) + b )
// one wave per node; f16x8 (16B) per lane; neighbor loop unrolled x8 for MLP.
__global__ __launch_bounds__(256) void prop_kernel(
    const _Float16* __restrict__ hs, const int* __restrict__ rowptr,
    const int* __restrict__ col, const float* __restrict__ dinv,
    const float* __restrict__ bias, _Float16* __restrict__ z) {
    int wid  = threadIdx.x >> 6;
    int lane = threadIdx.x & 63;
    int d = blockIdx.x * 4 + wid;                 // grid 2500 -> exactly 10000
    const char* base = (const char*)hs + lane * 16;
    f16x8 self = *(const f16x8*)(base + (size_t)d * 1024);
    float acc[8];
    #pragma unroll
    for (int i = 0; i < 8; ++i) acc[i] = (float)self[i];
    int jb = rowptr[d], je = rowptr[d + 1];
    int j = jb;
    for (; j + 8 <= je; j += 8) {
        int s0 = col[j],     s1 = col[j + 1], s2 = col[j + 2], s3 = col[j + 3];
        int s4 = col[j + 4], s5 = col[j + 5], s6 = col[j + 6], s7 = col[j + 7];
        f16x8 v0 = *(const f16x8*)(base + (size_t)s0 * 1024);
        f16x8 v1 = *(const f16x8*)(base + (size_t)s1 * 1024);
        f16x8 v2 = *(const f16x8*)(base + (size_t)s2 * 1024);
        f16x8 v3 = *(const f16x8*)(base + (size_t)s3 * 1024);
        f16x8 v4 = *(const f16x8*)(base + (size_t)s4 * 1024);
        f16x8 v5 = *(const f16x8*)(base + (size_t)s5 * 1024);
        f16x8 v6 = *(const f16x8*)(base + (size_t)s6 * 1024);
        f16x8 v7 = *(const f16x8*)(base + (size_t)s7 * 1024);
        #pragma unroll
        for (int i = 0; i < 8; ++i)
            acc[i] += (((float)v0[i] + (float)v1[i]) + ((float)v2[i] + (float)v3[i]))
                    + (((float)v4[i] + (float)v5[i]) + ((float)v6[i] + (float)v7[i]));
    }
    if (j + 4 <= je) {
        int s0 = col[j], s1 = col[j + 1], s2 = col[j + 2], s3 = col[j + 3];
        f16x8 v0 = *(const f16x8*)(base + (size_t)s0 * 1024);
        f16x8 v1 = *(const f16x8*)(base + (size_t)s1 * 1024);
        f16x8 v2 = *(const f16x8*)(base + (size_t)s2 * 1024);
        f16x8 v3 = *(const f16x8*)(base + (size_t)s3 * 1024);
        #pragma unroll
        for (int i = 0; i < 8; ++i)
            acc[i] += ((float)v0[i] + (float)v1[i]) + ((float)v2[i] + (float)v3[i]);
        j += 4;
    }
    for (; j < je; ++j) {
        int s = col[j];
        f16x8 v = *(const f16x8*)(base + (size_t)s * 1024);
        #pragma unroll
        for (int i = 0; i < 8; ++i) acc[i] += (float)v[i];
    }
    float dd = dinv[d];
    float4 b0 = *(const float4*)(bias + lane * 8);
    float4 b1 = *(const float4*)(bias + lane * 8 + 4);
    f16x8 o;
    o[0] = (_Float16)fmaxf(acc[0] * dd + b0.x, 0.0f);
    o[1] = (_Float16)fmaxf(acc[1] * dd + b0.y, 0.0f);
    o[2] = (_Float16)fmaxf(acc[2] * dd + b0.z, 0.0f);
    o[3] = (_Float16)fmaxf(acc[3] * dd + b0.w, 0.0f);
    o[4] = (_Float16)fmaxf(acc[4] * dd + b1.x, 0.0f);
    o[5] = (_Float16)fmaxf(acc[5] * dd + b1.y, 0.0f);
    o[6] = (_Float16)fmaxf(acc[6] * dd + b1.z, 0.0f);
    o[7] = (_Float16)fmaxf(acc[7] * dd + b1.w, 0.0f);
    *(f16x8*)((char*)z + (size_t)d * 1024 + lane * 16) = o;
}

// ---- pooling stage 1: per-(graph,chunk) partial sums, no atomics ------------
__global__ __launch_bounds__(64) void pool_kernel(
    const _Float16* __restrict__ z, const int* __restrict__ goff,
    float* __restrict__ partials) {
    int g = blockIdx.x, c = blockIdx.y;           // grid (64, PCHUNK)
    int lane = threadIdx.x;
    float acc[8] = {};
    int e = goff[g + 1];
    for (int n = goff[g] + c; n < e; n += PCHUNK) {
        f16x8 v = *(const f16x8*)((const char*)z + (size_t)n * 1024 + lane * 16);
        #pragma unroll
        for (int i = 0; i < 8; ++i) acc[i] += (float)v[i];
    }
    float* p = partials + ((size_t)c * NGRAPH + g) * FDIM + lane * 8;
    #pragma unroll
    for (int i = 0; i < 8; ++i) p[i] = acc[i];
}

// ---- final: reduce partials -> pooled output, then pooled @ Wlin + blin -----
__global__ void final_kernel(const float* __restrict__ partials, const float* __restrict__ Wlin,
                             const float* __restrict__ blin, float* __restrict__ pooled_out,
                             float* __restrict__ out) {
    __shared__ float p[FDIM];
    int g = blockIdx.x, t = threadIdx.x;          // 128 threads
    for (int i = t; i < FDIM; i += 128) {
        float s = 0.0f;
        #pragma unroll
        for (int c = 0; c < PCHUNK; ++c) s += partials[((size_t)c * NGRAPH + g) * FDIM + i];
        p[i] = s;
        pooled_out[g * FDIM + i] = s;
    }
    __syncthreads();
    float acc = blin[t];
    for (int k = 0; k < FDIM; ++k) acc += p[k] * Wlin[k * OUTF + t];
    out[g * OUTF + t] = acc;
}

// ---------------- launch -----------------------------------------------------
extern "C" void kernel_launch(void* const* d_in, const int* in_sizes, int n_in,
                              void* d_out, int out_size, void* d_ws, size_t ws_size,
                              hipStream_t stream) {
    const float*    x    = (const float*)d_in[0];
    const float*    W1   = (const float*)d_in[1];
    const float*    b1   = (const float*)d_in[2];
    const float*    W2   = (const float*)d_in[3];
    const float*    b2   = (const float*)d_in[4];
    const float*    Wlin = (const float*)d_in[5];
    const float*    blin = (const float*)d_in[6];
    const unsigned* eidx = (const unsigned*)d_in[7];
    const unsigned* bat  = (const unsigned*)d_in[8];
    float* out = (float*)d_out;

    char* w = (char*)d_ws;
    auto alloc = [&](size_t sz) { char* p = w; w += (sz + 255) & ~255ull; return p; };
    _Float16* buf0 = (_Float16*)alloc((size_t)MPAD * FDIM * 2);  // hs1
    _Float16* buf1 = (_Float16*)alloc((size_t)MPAD * FDIM * 2);  // z1, then z2
    _Float16* buf2 = (_Float16*)alloc((size_t)MPAD * FDIM * 2);  // hs2
    _Float16* W1T  = (_Float16*)alloc(512 * 512 * 2);
    _Float16* W2T  = (_Float16*)alloc(512 * 512 * 2);
    float* partials= (float*)alloc((size_t)PCHUNK * NGRAPH * FDIM * 4);
    int*   colA    = (int*)alloc(N_EDGES * 4);
    int*   rowptr  = (int*)alloc((N_NODES + 1) * 4);
    int*   fillcnt = (int*)alloc(N_NODES * 4);
    int*   deg_cnt = (int*)alloc(N_NODES * 4);
    float* dinv    = (float*)alloc(MPAD * 4);
    int*   goff    = (int*)alloc((NGRAPH + 1) * 4);
    int*   blocksum= (int*)alloc(PBLK * 4);

    // fused cooperative preprocessing (1 launch instead of 4)
    {
        void* args[] = {(void*)&eidx, (void*)&bat, (void*)&deg_cnt, (void*)&goff,
                        (void*)&dinv, (void*)&rowptr, (void*)&fillcnt, (void*)&colA,
                        (void*)&blocksum};
        hipLaunchCooperativeKernel((const void*)prep_coop, dim3(PBLK), dim3(256),
                                   args, 0, stream);
    }

    prep_w<<<dim3(8, 8, 2), 256, 0, stream>>>(W1, W2, W1T, W2T);

    const int NT = (MPAD / BM) * (FDIM / BN);                   // 632
    gemm_k<1><<<NT, 256, 0, stream>>>(x, W1T, dinv, buf0);      // hs1 = (x@W1)*dinv
    prop_kernel<<<N_NODES / 4, 256, 0, stream>>>(buf0, rowptr, colA, dinv, b1, buf1); // z1
    gemm_k<0><<<NT, 256, 0, stream>>>(buf1, W2T, dinv, buf2);   // hs2 = (z1@W2)*dinv
    prop_kernel<<<N_NODES / 4, 256, 0, stream>>>(buf2, rowptr, colA, dinv, b2, buf1); // z2

    pool_kernel<<<dim3(NGRAPH, PCHUNK), 64, 0, stream>>>(buf1, goff, partials);
    final_kernel<<<NGRAPH, 128, 0, stream>>>(partials, Wlin, blin, out, out + NGRAPH * FDIM);
}

// Round 9
// 139.030 us; speedup vs baseline: 1.2698x; 1.2698x over previous
//
#include <hip/hip_runtime.h>
#include <hip/hip_bf16.h>
#include <hip/hip_fp16.h>

#define N_NODES 10000
#define N_EDGES 160000
#define FDIM    512
#define MPAD    10112   // 158 * 64
#define NGRAPH  64
#define OUTF    128
#define PCHUNK  32      // pooling chunks per graph

typedef __attribute__((ext_vector_type(8))) _Float16 f16x8;
typedef __attribute__((ext_vector_type(4))) float    f32x4;

__device__ __forceinline__ void gload_lds16(const void* g, void* l) {
    __builtin_amdgcn_global_load_lds(
        (const __attribute__((address_space(1))) void*)g,
        (__attribute__((address_space(3))) void*)l, 16, 0, 0);
}

// ---- init: zero deg_cnt + dinv pad, detect int64/int32, graph offsets ------
__global__ void init_kernel(const unsigned* __restrict__ eraw, const unsigned* __restrict__ braw,
                            int* __restrict__ deg_cnt, int* __restrict__ goff,
                            int* __restrict__ flag, float* __restrict__ dinv) {
    int id = blockIdx.x * 256 + threadIdx.x;          // grid 40*256
    if (id < N_NODES) deg_cnt[id] = 0;
    if (id >= N_NODES && id < MPAD) dinv[id] = 0.0f;  // pad rows scale to 0
    if (blockIdx.x == 0) {
        __shared__ int s_is64;
        if (threadIdx.x < 64) {
            // edge_index values are random in [0,10000): if int64, every high
            // word is zero; if int32, odd words are real data (~0 prob all-zero).
            unsigned v = eraw[2 * threadIdx.x + 1];
            unsigned long long b = __ballot(v != 0u);
            if (threadIdx.x == 0) { s_is64 = (b == 0ull) ? 1 : 0; flag[0] = s_is64; }
        }
        __syncthreads();
        int g = threadIdx.x;
        if (g <= NGRAPH) {                    // batch is sorted: binary search
            int is64 = s_is64;
            int lo = 0, hi = N_NODES;
            while (lo < hi) {
                int mid = (lo + hi) >> 1;
                int b = (int)(is64 ? braw[2 * mid] : braw[mid]);
                if (b < g) lo = mid + 1; else hi = mid;
            }
            goff[g] = lo;
        }
    }
}

__global__ void extract_edges(const unsigned* __restrict__ raw, const int* __restrict__ flag,
                              int* __restrict__ deg_cnt) {
    int e = blockIdx.x * 256 + threadIdx.x;
    if (e >= N_EDGES) return;
    int is64 = flag[0];
    unsigned d = is64 ? raw[2 * (N_EDGES + e)] : raw[N_EDGES + e];
    atomicAdd(&deg_cnt[d], 1);
}

// single block, 1024 threads: rowptr/fillcnt = exclusive scan; dinv fused in.
__global__ __launch_bounds__(1024) void scan_kernel(
    const int* __restrict__ deg_cnt, int* __restrict__ rowptr,
    int* __restrict__ fillcnt, float* __restrict__ dinv) {
    __shared__ int sums[1024];
    int t = threadIdx.x;
    const int CH = 10;                       // 1024*10 >= 10000
    int start = t * CH, end = min(start + CH, N_NODES);
    int s = 0;
    for (int i = start; i < end; ++i) s += deg_cnt[i];
    sums[t] = s;
    __syncthreads();
    for (int off = 1; off < 1024; off <<= 1) {
        int v = (t >= off) ? sums[t - off] : 0;
        __syncthreads();
        sums[t] += v;
        __syncthreads();
    }
    int pre = (t == 0) ? 0 : sums[t - 1];
    for (int i = start; i < end; ++i) {
        int dc = deg_cnt[i];
        rowptr[i] = pre; fillcnt[i] = pre;
        dinv[i] = rsqrtf((float)(dc + 1));   // +1 self-loop
        pre += dc;
    }
    if (t == 1023) rowptr[N_NODES] = pre;
}

__global__ void scatter_kernel(const unsigned* __restrict__ raw, const int* __restrict__ flag,
                               int* __restrict__ fillcnt, int* __restrict__ col) {
    int e = blockIdx.x * 256 + threadIdx.x;
    if (e >= N_EDGES) return;
    int is64 = flag[0];
    unsigned s, d;
    if (is64) { s = raw[2 * e]; d = raw[2 * (N_EDGES + e)]; }
    else      { s = raw[e];     d = raw[N_EDGES + e]; }
    int idx = atomicAdd(&fillcnt[d], 1);
    col[idx] = (int)s;
}

// W[k][n] (512x512 row-major) -> WT[n][k] as f16, LDS tile transpose
__global__ __launch_bounds__(256) void prep_w(
    const float* __restrict__ W1, const float* __restrict__ W2,
    _Float16* __restrict__ W1T, _Float16* __restrict__ W2T) {
    __shared__ float tile[64][65];
    const float* W = blockIdx.z ? W2 : W1;
    _Float16*   T  = blockIdx.z ? W2T : W1T;
    int r0 = blockIdx.y * 64, c0 = blockIdx.x * 64;
    int t = threadIdx.x;
    int col = t & 63, rr = t >> 6;
    #pragma unroll
    for (int i = 0; i < 16; ++i) {
        int row = i * 4 + rr;
        tile[row][col] = W[(size_t)(r0 + row) * 512 + c0 + col];   // coalesced read
    }
    __syncthreads();
    #pragma unroll
    for (int i = 0; i < 16; ++i) {
        int orow = i * 4 + rr;                                     // output row = orig col
        T[(size_t)(c0 + orow) * 512 + r0 + col] = (_Float16)tile[col][orow]; // coalesced write
    }
}

// -------- GEMM: C[r][c] = dinv[r] * (A[Mpad,512] @ B)[r][c]   (B as Bt[n][k])
// 64x128 tile, 632 blocks (2.47/CU). 4 waves: each owns 64 rows x 32 cols.
// AF32=1: A is f32 [N_NODES,512], converted to f16 during reg-staging.
#define BM 64
#define BN 128
#define BK 64

template<int AF32>
__global__ __launch_bounds__(256) void gemm_k(
    const void* __restrict__ Av, const _Float16* __restrict__ Bt,
    const float* __restrict__ dinv, _Float16* __restrict__ C) {
    __shared__ __align__(16) _Float16 Asm[BM * BK];
    __shared__ __align__(16) _Float16 Bsm[BN * BK];
    char* As = (char*)Asm;
    char* Bs = (char*)Bsm;
    const char* Ab = (const char*)Av;
    const char* Bb = (const char*)Bt;

    int tid  = threadIdx.x;
    int lane = tid & 63;
    int wave = tid >> 6;                    // 4 waves; wave w owns cols w*32..w*32+31

    // bijective XCD swizzle: NT=632, q=79, r=0 -> tile = xcd*79 + sub.
    const int NT = (MPAD / BM) * (FDIM / BN);          // 632
    int bid = blockIdx.x;
    int xcd = bid & 7, sub = bid >> 3;
    int q = NT >> 3, r = NT & 7;                       // 79, 0
    int base = (xcd < r) ? xcd * (q + 1) : r * (q + 1) + (xcd - r) * q;
    int tile = base + sub;
    int m0 = (tile >> 2) * BM;
    int n0 = (tile & 3) * BN;

    f32x4 acc[4][2] = {};

    for (int kt = 0; kt < FDIM; kt += BK) {
        if (AF32) {
            // reg-stage A: f32 global (linear) -> cvt f16 -> swizzled ds_write
            #pragma unroll
            for (int c = 0; c < 2; ++c) {
                int o   = (tid + c * 256) * 16;        // linear f16-tile byte offset
                int row = o >> 7;
                int cb  = o & 127;
                int gr  = m0 + row;
                f16x8 hv = (f16x8)0;
                if (gr < N_NODES) {
                    const float* sp = (const float*)(Ab + (size_t)gr * 2048 +
                                                     (size_t)kt * 4 + cb * 2);
                    float4 v0 = *(const float4*)sp;
                    float4 v1 = *(const float4*)(sp + 4);
                    hv[0] = (_Float16)v0.x; hv[1] = (_Float16)v0.y;
                    hv[2] = (_Float16)v0.z; hv[3] = (_Float16)v0.w;
                    hv[4] = (_Float16)v1.x; hv[5] = (_Float16)v1.y;
                    hv[6] = (_Float16)v1.z; hv[7] = (_Float16)v1.w;
                }
                *(f16x8*)(As + row * 128 + (cb ^ ((row & 7) << 4))) = hv;
            }
            #pragma unroll
            for (int i = 0; i < 4; ++i) {
                int o   = i * 4096 + wave * 1024 + lane * 16;
                int row = o >> 7;
                int cb  = o & 127;
                int scb = cb ^ ((row & 7) << 4);
                gload_lds16(Bb + (size_t)(n0 + row) * 1024 + kt * 2 + scb,
                            Bs + i * 4096 + wave * 1024);
            }
        } else {
            #pragma unroll
            for (int c = 0; c < 2; ++c) {          // A-tile: 8KB = 2 rounds
                int o   = c * 4096 + wave * 1024 + lane * 16;
                int row = o >> 7;
                int cb  = o & 127;
                int scb = cb ^ ((row & 7) << 4);
                gload_lds16(Ab + (size_t)(m0 + row) * 1024 + kt * 2 + scb,
                            As + c * 4096 + wave * 1024);
            }
            #pragma unroll
            for (int i = 0; i < 4; ++i) {          // B-tile: 16KB = 4 rounds
                int o   = i * 4096 + wave * 1024 + lane * 16;
                int row = o >> 7;
                int cb  = o & 127;
                int scb = cb ^ ((row & 7) << 4);
                gload_lds16(Bb + (size_t)(n0 + row) * 1024 + kt * 2 + scb,
                            Bs + i * 4096 + wave * 1024);
            }
        }
        __syncthreads();   // drains vmcnt + lgkmcnt before LDS reads

        #pragma unroll
        for (int kk = 0; kk < 2; ++kk) {
            f16x8 af[4], bf[2];
            int kb = kk * 64 + ((lane >> 4) << 4);        // byte offset in row
            #pragma unroll
            for (int fm = 0; fm < 4; ++fm) {              // rows 0..63 (broadcast across waves)
                int rr = fm * 16 + (lane & 15);
                af[fm] = *(const f16x8*)(As + rr * 128 + (kb ^ ((rr & 7) << 4)));
            }
            #pragma unroll
            for (int fn = 0; fn < 2; ++fn) {              // cols wave*32 + fn*16
                int rr = wave * 32 + fn * 16 + (lane & 15);
                bf[fn] = *(const f16x8*)(Bs + rr * 128 + (kb ^ ((rr & 7) << 4)));
            }
            #pragma unroll
            for (int fm = 0; fm < 4; ++fm)
                #pragma unroll
                for (int fn = 0; fn < 2; ++fn)
                    acc[fm][fn] = __builtin_amdgcn_mfma_f32_16x16x32_f16(
                        af[fm], bf[fn], acc[fm][fn], 0, 0, 0);
        }
        __syncthreads();
    }

    #pragma unroll
    for (int fm = 0; fm < 4; ++fm) {
        #pragma unroll
        for (int r4 = 0; r4 < 4; ++r4) {
            int row = m0 + fm * 16 + ((lane >> 4) << 2) + r4;
            float dr = dinv[row];
            #pragma unroll
            for (int fn = 0; fn < 2; ++fn) {
                int cn = n0 + wave * 32 + fn * 16 + (lane & 15);
                C[(size_t)row * FDIM + cn] = (_Float16)(acc[fm][fn][r4] * dr);
            }
        }
    }
}

// ---- propagation: z[d] = relu( dinv[d] * (sum_{s in N(d)} hs[s] + hs[d]) + b )
// one wave per node; f16x8 (16B) per lane. Neighbor indices are loaded once
// per 64 via a coalesced lane-load, then broadcast with __shfl (VALU) so the
// VMEM queue is reserved for the 1KB row gathers (8 in flight).
__global__ __launch_bounds__(256) void prop_kernel(
    const _Float16* __restrict__ hs, const int* __restrict__ rowptr,
    const int* __restrict__ col, const float* __restrict__ dinv,
    const float* __restrict__ bias, _Float16* __restrict__ z) {
    int wid  = threadIdx.x >> 6;
    int lane = threadIdx.x & 63;
    int d = blockIdx.x * 4 + wid;                 // grid 2500 -> exactly 10000
    const char* base = (const char*)hs + lane * 16;
    f16x8 self = *(const f16x8*)(base + (size_t)d * 1024);
    float acc[8];
    #pragma unroll
    for (int i = 0; i < 8; ++i) acc[i] = (float)self[i];
    int jb = rowptr[d], je = rowptr[d + 1];
    for (int bj = jb; bj < je; bj += 64) {
        int n = je - bj; if (n > 64) n = 64;
        int sidx = (lane < n) ? col[bj + lane] : 0;
        int k = 0;
        for (; k + 8 <= n; k += 8) {
            int s0 = __shfl(sidx, k + 0), s1 = __shfl(sidx, k + 1);
            int s2 = __shfl(sidx, k + 2), s3 = __shfl(sidx, k + 3);
            int s4 = __shfl(sidx, k + 4), s5 = __shfl(sidx, k + 5);
            int s6 = __shfl(sidx, k + 6), s7 = __shfl(sidx, k + 7);
            f16x8 v0 = *(const f16x8*)(base + (size_t)s0 * 1024);
            f16x8 v1 = *(const f16x8*)(base + (size_t)s1 * 1024);
            f16x8 v2 = *(const f16x8*)(base + (size_t)s2 * 1024);
            f16x8 v3 = *(const f16x8*)(base + (size_t)s3 * 1024);
            f16x8 v4 = *(const f16x8*)(base + (size_t)s4 * 1024);
            f16x8 v5 = *(const f16x8*)(base + (size_t)s5 * 1024);
            f16x8 v6 = *(const f16x8*)(base + (size_t)s6 * 1024);
            f16x8 v7 = *(const f16x8*)(base + (size_t)s7 * 1024);
            #pragma unroll
            for (int i = 0; i < 8; ++i)
                acc[i] += (((float)v0[i] + (float)v1[i]) + ((float)v2[i] + (float)v3[i]))
                        + (((float)v4[i] + (float)v5[i]) + ((float)v6[i] + (float)v7[i]));
        }
        if (k + 4 <= n) {
            int s0 = __shfl(sidx, k + 0), s1 = __shfl(sidx, k + 1);
            int s2 = __shfl(sidx, k + 2), s3 = __shfl(sidx, k + 3);
            f16x8 v0 = *(const f16x8*)(base + (size_t)s0 * 1024);
            f16x8 v1 = *(const f16x8*)(base + (size_t)s1 * 1024);
            f16x8 v2 = *(const f16x8*)(base + (size_t)s2 * 1024);
            f16x8 v3 = *(const f16x8*)(base + (size_t)s3 * 1024);
            #pragma unroll
            for (int i = 0; i < 8; ++i)
                acc[i] += ((float)v0[i] + (float)v1[i]) + ((float)v2[i] + (float)v3[i]);
            k += 4;
        }
        for (; k < n; ++k) {
            int s = __shfl(sidx, k);
            f16x8 v = *(const f16x8*)(base + (size_t)s * 1024);
            #pragma unroll
            for (int i = 0; i < 8; ++i) acc[i] += (float)v[i];
        }
    }
    float dd = dinv[d];
    float4 b0 = *(const float4*)(bias + lane * 8);
    float4 b1 = *(const float4*)(bias + lane * 8 + 4);
    f16x8 o;
    o[0] = (_Float16)fmaxf(acc[0] * dd + b0.x, 0.0f);
    o[1] = (_Float16)fmaxf(acc[1] * dd + b0.y, 0.0f);
    o[2] = (_Float16)fmaxf(acc[2] * dd + b0.z, 0.0f);
    o[3] = (_Float16)fmaxf(acc[3] * dd + b0.w, 0.0f);
    o[4] = (_Float16)fmaxf(acc[4] * dd + b1.x, 0.0f);
    o[5] = (_Float16)fmaxf(acc[5] * dd + b1.y, 0.0f);
    o[6] = (_Float16)fmaxf(acc[6] * dd + b1.z, 0.0f);
    o[7] = (_Float16)fmaxf(acc[7] * dd + b1.w, 0.0f);
    *(f16x8*)((char*)z + (size_t)d * 1024 + lane * 16) = o;
}

// ---- pooling stage 1: per-(graph,chunk) partial sums, no atomics ------------
__global__ __launch_bounds__(64) void pool_kernel(
    const _Float16* __restrict__ z, const int* __restrict__ goff,
    float* __restrict__ partials) {
    int g = blockIdx.x, c = blockIdx.y;           // grid (64, PCHUNK)
    int lane = threadIdx.x;
    float acc[8] = {};
    int e = goff[g + 1];
    for (int n = goff[g] + c; n < e; n += PCHUNK) {
        f16x8 v = *(const f16x8*)((const char*)z + (size_t)n * 1024 + lane * 16);
        #pragma unroll
        for (int i = 0; i < 8; ++i) acc[i] += (float)v[i];
    }
    float* p = partials + ((size_t)c * NGRAPH + g) * FDIM + lane * 8;
    #pragma unroll
    for (int i = 0; i < 8; ++i) p[i] = acc[i];
}

// ---- final: reduce partials -> pooled output, then pooled @ Wlin + blin -----
__global__ void final_kernel(const float* __restrict__ partials, const float* __restrict__ Wlin,
                             const float* __restrict__ blin, float* __restrict__ pooled_out,
                             float* __restrict__ out) {
    __shared__ float p[FDIM];
    int g = blockIdx.x, t = threadIdx.x;          // 128 threads
    for (int i = t; i < FDIM; i += 128) {
        float s = 0.0f;
        #pragma unroll
        for (int c = 0; c < PCHUNK; ++c) s += partials[((size_t)c * NGRAPH + g) * FDIM + i];
        p[i] = s;
        pooled_out[g * FDIM + i] = s;
    }
    __syncthreads();
    float acc = blin[t];
    for (int k = 0; k < FDIM; ++k) acc += p[k] * Wlin[k * OUTF + t];
    out[g * OUTF + t] = acc;
}

// ---------------- launch -----------------------------------------------------
extern "C" void kernel_launch(void* const* d_in, const int* in_sizes, int n_in,
                              void* d_out, int out_size, void* d_ws, size_t ws_size,
                              hipStream_t stream) {
    const float*    x    = (const float*)d_in[0];
    const float*    W1   = (const float*)d_in[1];
    const float*    b1   = (const float*)d_in[2];
    const float*    W2   = (const float*)d_in[3];
    const float*    b2   = (const float*)d_in[4];
    const float*    Wlin = (const float*)d_in[5];
    const float*    blin = (const float*)d_in[6];
    const unsigned* eidx = (const unsigned*)d_in[7];
    const unsigned* bat  = (const unsigned*)d_in[8];
    float* out = (float*)d_out;

    char* w = (char*)d_ws;
    auto alloc = [&](size_t sz) { char* p = w; w += (sz + 255) & ~255ull; return p; };
    _Float16* buf0 = (_Float16*)alloc((size_t)MPAD * FDIM * 2);  // hs1
    _Float16* buf1 = (_Float16*)alloc((size_t)MPAD * FDIM * 2);  // z1, then z2
    _Float16* buf2 = (_Float16*)alloc((size_t)MPAD * FDIM * 2);  // hs2
    _Float16* W1T  = (_Float16*)alloc(512 * 512 * 2);
    _Float16* W2T  = (_Float16*)alloc(512 * 512 * 2);
    float* partials= (float*)alloc((size_t)PCHUNK * NGRAPH * FDIM * 4);
    int*   colA    = (int*)alloc(N_EDGES * 4);
    int*   rowptr  = (int*)alloc((N_NODES + 1) * 4);
    int*   fillcnt = (int*)alloc(N_NODES * 4);
    int*   deg_cnt = (int*)alloc(N_NODES * 4);
    float* dinv    = (float*)alloc(MPAD * 4);
    int*   goff    = (int*)alloc((NGRAPH + 1) * 4);
    int*   flag    = (int*)alloc(16);

    // graph preprocessing (4 small launches; beats grid.sync on this chip)
    init_kernel<<<40, 256, 0, stream>>>(eidx, bat, deg_cnt, goff, flag, dinv);
    extract_edges<<<(N_EDGES + 255) / 256, 256, 0, stream>>>(eidx, flag, deg_cnt);
    scan_kernel<<<1, 1024, 0, stream>>>(deg_cnt, rowptr, fillcnt, dinv);
    scatter_kernel<<<(N_EDGES + 255) / 256, 256, 0, stream>>>(eidx, flag, fillcnt, colA);

    prep_w<<<dim3(8, 8, 2), 256, 0, stream>>>(W1, W2, W1T, W2T);

    const int NT = (MPAD / BM) * (FDIM / BN);                   // 632
    gemm_k<1><<<NT, 256, 0, stream>>>(x, W1T, dinv, buf0);      // hs1 = (x@W1)*dinv
    prop_kernel<<<N_NODES / 4, 256, 0, stream>>>(buf0, rowptr, colA, dinv, b1, buf1); // z1
    gemm_k<0><<<NT, 256, 0, stream>>>(buf1, W2T, dinv, buf2);   // hs2 = (z1@W2)*dinv
    prop_kernel<<<N_NODES / 4, 256, 0, stream>>>(buf2, rowptr, colA, dinv, b2, buf1); // z2

    pool_kernel<<<dim3(NGRAPH, PCHUNK), 64, 0, stream>>>(buf1, goff, partials);
    final_kernel<<<NGRAPH, 128, 0, stream>>>(partials, Wlin, blin, out, out + NGRAPH * FDIM);
}